// Round 9
// baseline (113.114 us; speedup 1.0000x reference)
//
#include <hip/hip_runtime.h>

#define NB 4
#define NN 256
#define ND 512
#define NITER 10

typedef _Float16 half_t;
typedef __attribute__((ext_vector_type(8))) unsigned short ushort8v;
typedef __attribute__((ext_vector_type(8))) _Float16 half8v;
typedef __attribute__((ext_vector_type(2))) _Float16 half2v;

__device__ __forceinline__ unsigned short f2bf(float x) {
  unsigned u = __float_as_uint(x);
  u += 0x7fffu + ((u >> 16) & 1u);   // round-to-nearest-even
  return (unsigned short)(u >> 16);
}
__device__ __forceinline__ float bf2f(unsigned short h) {
  return __uint_as_float(((unsigned)h) << 16);
}

// ---------------------------------------------------------------- softmax ---
// one block per row; 2048 rows total (p_s then p_t). fp16 output.
// Block 0 also zeroes d_out (stream-ordered before sink_k's atomicAdd).
__global__ __launch_bounds__(256) void softmax_k(const float* __restrict__ ys,
                                                 const float* __restrict__ yt,
                                                 half_t* __restrict__ ps,
                                                 half_t* __restrict__ pt,
                                                 float* __restrict__ out) {
  int bb = blockIdx.x;
  if (bb == 0 && threadIdx.x == 0) out[0] = 0.0f;
  const float* src = (bb < NB * NN) ? ys : yt;
  half_t* dst      = (bb < NB * NN) ? ps : pt;
  int row = bb & (NB * NN - 1);
  const float* rp = src + (size_t)row * ND;
  half_t* wp = dst + (size_t)row * ND;
  int t = threadIdx.x;
  float a = rp[t];
  float b = rp[t + 256];
  float m = fmaxf(a, b);
  #pragma unroll
  for (int s = 1; s < 64; s <<= 1) m = fmaxf(m, __shfl_xor(m, s));
  __shared__ float red[4];
  int wid = t >> 6;
  if ((t & 63) == 0) red[wid] = m;
  __syncthreads();
  m = fmaxf(fmaxf(red[0], red[1]), fmaxf(red[2], red[3]));
  float e0 = expf((a - m) * 0.5f);   // softmax(y/2)
  float e1 = expf((b - m) * 0.5f);
  float ssum = e0 + e1;
  #pragma unroll
  for (int s = 1; s < 64; s <<= 1) ssum += __shfl_xor(ssum, s);
  __syncthreads();
  if ((t & 63) == 0) red[wid] = ssum;
  __syncthreads();
  ssum = red[0] + red[1] + red[2] + red[3];
  float inv = 1.0f / ssum;
  wp[t]       = (half_t)(e0 * inv);
  wp[t + 256] = (half_t)(e1 * inv);
}

// ------------------------------------------------------------ cost matrix ---
// W fp16 AND K = bf16(exp(-10*min(W,10)) + 1e-8) to global; exp here is
// distributed over 256 CUs (~256 cyc/WG) instead of serialized in sink_k.
__global__ __launch_bounds__(256) void cost_k(const half_t* __restrict__ ps,
                                              const half_t* __restrict__ pt,
                                              half_t* __restrict__ W,
                                              unsigned short* __restrict__ Kg) {
  __shared__ half_t xs[32 * 512];   // 32 KiB
  __shared__ half_t ysh[32 * 512];  // 32 KiB
  int b  = blockIdx.z;
  int It = blockIdx.y * 32;
  int Jt = blockIdx.x * 32;
  int t = threadIdx.x;
  const half8v* xg = reinterpret_cast<const half8v*>(ps + ((size_t)b * NN + It) * ND);
  const half8v* yg = reinterpret_cast<const half8v*>(pt + ((size_t)b * NN + Jt) * ND);
  half8v* xsv = reinterpret_cast<half8v*>(xs);
  half8v* ysv = reinterpret_cast<half8v*>(ysh);
  #pragma unroll
  for (int s = 0; s < 8; ++s) {
    int qidx = s * 256 + t;        // quad index 0..2047 (= r*64 + q)
    int r = qidx >> 6;
    int q = qidx & 63;
    int rot = (r + (r >> 3)) & 7;
    int dst = r * 64 + ((q + rot) & 63);
    xsv[dst] = xg[qidx];
    ysv[dst] = yg[qidx];
  }
  __syncthreads();
  int tx = t & 15, ty = t >> 4;
  int i0 = 2 * ty, j0 = 2 * tx;
  int rx0 = (i0 + (i0 >> 3)) & 7;
  int rx1 = ((i0 + 1) + ((i0 + 1) >> 3)) & 7;
  int ry0 = (j0 + (j0 >> 3)) & 7;
  int ry1 = ((j0 + 1) + ((j0 + 1) >> 3)) & 7;
  float a00 = 0.f, a01 = 0.f, a10 = 0.f, a11 = 0.f;
  #pragma unroll 4
  for (int qq = 0; qq < 64; ++qq) {
    half8v x0 = xsv[i0 * 64 + ((qq + rx0) & 63)];
    half8v x1 = xsv[(i0 + 1) * 64 + ((qq + rx1) & 63)];
    half8v y0 = ysv[j0 * 64 + ((qq + ry0) & 63)];
    half8v y1 = ysv[(j0 + 1) * 64 + ((qq + ry1) & 63)];
    #pragma unroll
    for (int e = 0; e < 8; ++e) {
      float xf0 = (float)x0[e], xf1 = (float)x1[e];
      float yf0 = (float)y0[e], yf1 = (float)y1[e];
      a00 += fabsf(xf0 - yf0);
      a01 += fabsf(xf0 - yf1);
      a10 += fabsf(xf1 - yf0);
      a11 += fabsf(xf1 - yf1);
    }
  }
  size_t base = ((size_t)b * NN + It + i0) * NN + Jt + j0;
  half_t* wb = W + base;
  half2v w0; w0[0] = (half_t)a00; w0[1] = (half_t)a01;
  half2v w1; w1[0] = (half_t)a10; w1[1] = (half_t)a11;
  *reinterpret_cast<half2v*>(wb)      = w0;
  *reinterpret_cast<half2v*>(wb + NN) = w1;
  // K from fp32 W (more accurate than via fp16)
  ushort2 k0, k1;
  k0.x = f2bf(__expf(fminf(a00, 10.0f) * -10.0f) + 1e-8f);
  k0.y = f2bf(__expf(fminf(a01, 10.0f) * -10.0f) + 1e-8f);
  k1.x = f2bf(__expf(fminf(a10, 10.0f) * -10.0f) + 1e-8f);
  k1.y = f2bf(__expf(fminf(a11, 10.0f) * -10.0f) + 1e-8f);
  *reinterpret_cast<ushort2*>(Kg + base)      = k0;
  *reinterpret_cast<ushort2*>(Kg + base + NN) = k1;
}

// ---------------------------------------------------------------- sinkhorn ---
// P = diag(u) K diag(v); K bf16 in LDS (XOR swizzle pj = j ^ ((i&7)<<3)).
// One WG/batch, 1024 thr. u,v in REGISTERS (consistently replicated);
// bf16 shadows usbT (transposed, quad-swizzled) / vsb (quad-swizzled) carry
// values between passes. Quad qd lives at slot (qd ^ (qd>>3)); NOTE slots of
// adjacent quads are NOT adjacent when (qd>>3) is odd -- each quad's slot
// must be computed independently (round-8 NaN bug: assumed upos+8).
__global__ __launch_bounds__(1024) void sink_k(const unsigned short* __restrict__ Kgl,
                                               const half_t* __restrict__ Wg,
                                               float* __restrict__ out) {
  __shared__ __align__(16) unsigned short Kl[NN * NN];   // 128 KiB
  __shared__ __align__(16) unsigned short usbT[NN];      // bf16 u, transposed+swz
  __shared__ __align__(16) unsigned short vsb[NN];       // bf16 v, quad-swz
  __shared__ __align__(16) float u_l[NN];
  __shared__ __align__(16) float v_l[NN];
  __shared__ float red[16];
  int b = blockIdx.x;
  int t = threadIdx.x;
  int w = t >> 6, l = t & 63;
  int l16 = l & 15, grp = l >> 4;

  // ---- build: copy K (global bf16, linear) -> LDS swizzled
  const ushort8v* Kg8 = reinterpret_cast<const ushort8v*>(Kgl + (size_t)b * NN * NN);
  #pragma unroll
  for (int s = 0; s < 8; ++s) {
    int q8 = s * 1024 + t;
    int i = q8 >> 5;
    int j = (q8 & 31) * 8;
    ushort8v kk = Kg8[q8];
    *reinterpret_cast<ushort8v*>(&Kl[i * 256 + (j ^ ((i & 7) << 3))]) = kk;
  }
  if (t < NN) { usbT[t] = 0x3F80u; vsb[t] = 0x3F80u; }  // bf16(1.0)
  __syncthreads();

  // ownership
  int irow = w * 16 + l16;                 // row-pass row
  const int swr = (irow & 7) << 3;
  float uo = 1.0f;
  int jc = w * 16 + 4 * (l & 3);           // col-pass 4-col base
  int rch = l >> 2;                        // col-pass row-chunk (rows rch+16*rr)
  float vo0 = 1.f, vo1 = 1.f, vo2 = 1.f, vo3 = 1.f;

  for (int it = 0; it < NITER; ++it) {
    // ---- ROW: r_i = sum_j K[i][j] v[j]; lane covers j in [64*grp, +64)
    float r = 0.0f;
    #pragma unroll
    for (int q = 0; q < 8; ++q) {
      int vpos = (8 * grp + q) ^ grp;                       // slot of quad 8*grp+q
      ushort8v v8 = *reinterpret_cast<const ushort8v*>(&vsb[vpos * 8]);
      int j0 = 64 * grp + 8 * q;
      ushort8v k8 = *reinterpret_cast<const ushort8v*>(&Kl[irow * 256 + (j0 ^ swr)]);
      r += bf2f(k8[0]) * bf2f(v8[0]) + bf2f(k8[1]) * bf2f(v8[1]) +
           bf2f(k8[2]) * bf2f(v8[2]) + bf2f(k8[3]) * bf2f(v8[3]) +
           bf2f(k8[4]) * bf2f(v8[4]) + bf2f(k8[5]) * bf2f(v8[5]) +
           bf2f(k8[6]) * bf2f(v8[6]) + bf2f(k8[7]) * bf2f(v8[7]);
    }
    r += __shfl_xor(r, 16);
    r += __shfl_xor(r, 32);                 // all 4 grp-lanes: full r_i (bitwise eq)
    uo = uo / fmaxf(uo * r, 1e-8f);
    if (grp == 0) {
      int tau = l16 * 16 + w;               // transposed index (irow&15)*16 + irow>>4
      int qd = tau >> 3;
      usbT[(qd ^ (qd >> 3)) * 8 + (tau & 7)] = f2bf(uo);
    }
    __syncthreads();

    // ---- COL: c_j, j in [jc, jc+4); lane rows {rch + 16*rr}
    int qd2 = 2 * rch;
    int sq = rch >> 2;                      // == qd2>>3 == (qd2+1)>>3 (qd2 even)
    int slot_a = qd2 ^ sq;                  // slot of quad qd2
    int slot_b = (qd2 + 1) ^ sq;            // slot of quad qd2+1 (FIX: independent)
    ushort8v u8a = *reinterpret_cast<const ushort8v*>(&usbT[slot_a * 8]);
    ushort8v u8b = *reinterpret_cast<const ushort8v*>(&usbT[slot_b * 8]);
    float c0 = 0.f, c1 = 0.f, c2 = 0.f, c3 = 0.f;
    #pragma unroll
    for (int rr = 0; rr < 16; ++rr) {
      int i = rch + 16 * rr;
      ushort4 k4 = *reinterpret_cast<const ushort4*>(&Kl[i * 256 + (jc ^ ((i & 7) << 3))]);
      float uf = bf2f(rr < 8 ? u8a[rr] : u8b[rr - 8]);
      c0 += bf2f(k4.x) * uf; c1 += bf2f(k4.y) * uf;
      c2 += bf2f(k4.z) * uf; c3 += bf2f(k4.w) * uf;
    }
    #pragma unroll
    for (int m = 4; m <= 32; m <<= 1) {
      c0 += __shfl_xor(c0, m); c1 += __shfl_xor(c1, m);
      c2 += __shfl_xor(c2, m); c3 += __shfl_xor(c3, m);
    }
    vo0 = vo0 / fmaxf(vo0 * c0, 1e-8f);
    vo1 = vo1 / fmaxf(vo1 * c1, 1e-8f);
    vo2 = vo2 / fmaxf(vo2 * c2, 1e-8f);
    vo3 = vo3 / fmaxf(vo3 * c3, 1e-8f);
    if (rch == 0) {                         // lanes 0..3 own cols jc..jc+3
      int qd_v = jc >> 3;
      int vpos2 = (qd_v ^ (qd_v >> 3)) * 8 + (jc & 7);
      ushort4 vv;
      vv.x = f2bf(vo0); vv.y = f2bf(vo1); vv.z = f2bf(vo2); vv.w = f2bf(vo3);
      *reinterpret_cast<ushort4*>(&vsb[vpos2]) = vv;
    }
    __syncthreads();
  }

  // ---- publish fp32 u,v for the loss
  if (grp == 0) u_l[irow] = uo;
  if (rch == 0) {
    v_l[jc] = vo0; v_l[jc + 1] = vo1; v_l[jc + 2] = vo2; v_l[jc + 3] = vo3;
  }
  __syncthreads();

  // ---- loss = sum_ij u_i K_ij v_j W_ij  (W unclipped fp16)
  const half8v* W8 = reinterpret_cast<const half8v*>(Wg + (size_t)b * NN * NN);
  float acc = 0.0f;
  #pragma unroll
  for (int s = 0; s < 8; ++s) {
    int q8 = s * 1024 + t;
    int i = q8 >> 5;
    int j = (q8 & 31) * 8;
    half8v w8 = W8[q8];
    ushort8v k8 = *reinterpret_cast<const ushort8v*>(&Kl[i * 256 + (j ^ ((i & 7) << 3))]);
    float ui = u_l[i];
    float4 v0 = *reinterpret_cast<const float4*>(&v_l[j]);
    float4 v1 = *reinterpret_cast<const float4*>(&v_l[j + 4]);
    acc += ui * (bf2f(k8[0]) * v0.x * (float)w8[0] + bf2f(k8[1]) * v0.y * (float)w8[1] +
                 bf2f(k8[2]) * v0.z * (float)w8[2] + bf2f(k8[3]) * v0.w * (float)w8[3] +
                 bf2f(k8[4]) * v1.x * (float)w8[4] + bf2f(k8[5]) * v1.y * (float)w8[5] +
                 bf2f(k8[6]) * v1.z * (float)w8[6] + bf2f(k8[7]) * v1.w * (float)w8[7]);
  }
  #pragma unroll
  for (int s = 1; s < 64; s <<= 1) acc += __shfl_xor(acc, s);
  __syncthreads();
  if (l == 0) red[w] = acc;
  __syncthreads();
  if (t == 0) {
    float tot = 0.0f;
    #pragma unroll
    for (int q = 0; q < 16; ++q) tot += red[q];
    atomicAdd(out, 2.5e-4f * tot);   // 0.001 * mean over 4 batches
  }
}

// ----------------------------------------------------------------- launch ---
extern "C" void kernel_launch(void* const* d_in, const int* in_sizes, int n_in,
                              void* d_out, int out_size, void* d_ws, size_t ws_size,
                              hipStream_t stream) {
  const float* ys = (const float*)d_in[0];
  const float* yt = (const float*)d_in[1];
  half_t* ps = (half_t*)d_ws;                          // 1 MiB
  half_t* pt = ps + (size_t)NB * NN * ND;              // 1 MiB
  half_t* W  = pt + (size_t)NB * NN * ND;              // 512 KiB
  unsigned short* Kg = (unsigned short*)(W + (size_t)NB * NN * NN); // 512 KiB
  float* out = (float*)d_out;

  softmax_k<<<2 * NB * NN, 256, 0, stream>>>(ys, yt, ps, pt, out);
  cost_k<<<dim3(8, 8, NB), 256, 0, stream>>>(ps, pt, W, Kg);
  sink_k<<<NB, 1024, 0, stream>>>(Kg, W, out);
}